// Round 11
// baseline (190.030 us; speedup 1.0000x reference)
//
#include <hip/hip_runtime.h>

#define N_NODES 100000
#define N_EDGES 1600000
#define IN_FEAT 128
#define OUT_FEAT 64
#define SLOPE 0.22916666666666666f  // (1/8 + 1/3)/2 = 11/48

#define NPB 128            // nodes per bucket
#define NB 782             // ceil(N_NODES / NPB)
#define CAP 2560           // static bucket capacity (mean 2046 -> 11+ sigma margin)
#define BIN_CHUNK 8192     // edges per binning block
#define EPT 32             // edges per thread in binning (BIN_CHUNK/256)
#define BIN_BLOCKS ((N_EDGES + BIN_CHUNK - 1) / BIN_CHUNK)  // 196
#define GEMM1_BLOCKS (N_NODES / 16)                         // 6250

__device__ __forceinline__ ushort f2bf(float x) {
    unsigned u = __float_as_uint(x);
    u += 0x7FFFu + ((u >> 16) & 1u);  // round to nearest even
    return (ushort)(u >> 16);
}

// ---------------------------------------------------------------------------
// Binning (standalone): dense per-block runs of packed ((dst&127)<<17 | src)
// into static per-bucket windows [b*CAP, (b+1)*CAP).
// ---------------------------------------------------------------------------
__global__ __launch_bounds__(256) void binning_kernel(const int* __restrict__ src,
                                                      const int* __restrict__ dst,
                                                      int* __restrict__ bcur,
                                                      int* __restrict__ pairs) {
    __shared__ int cnt[NB];
    __shared__ int gbase[NB];
    for (int i = threadIdx.x; i < NB; i += 256) cnt[i] = 0;
    __syncthreads();
    const int base = blockIdx.x * BIN_CHUNK;
    int bl[EPT];  // (bucket<<13) | local_rank, or -1
    int vp[EPT];  // packed payload
#pragma unroll
    for (int i = 0; i < EPT; ++i) {
        const int e = base + i * 256 + threadIdx.x;
        if (e < N_EDGES) {
            const int d = dst[e];
            const int b = d >> 7;
            const int lpos = atomicAdd(&cnt[b], 1);
            bl[i] = (b << 13) | lpos;
            vp[i] = ((d & 127) << 17) | src[e];
        } else {
            bl[i] = -1;
        }
    }
    __syncthreads();
    for (int i = threadIdx.x; i < NB; i += 256) {
        const int c = cnt[i];
        gbase[i] = c ? (i * CAP + atomicAdd(&bcur[i], c)) : 0;
    }
    __syncthreads();
#pragma unroll
    for (int i = 0; i < EPT; ++i) {
        if (bl[i] >= 0) {
            const int b = bl[i] >> 13, lpos = bl[i] & 8191;
            pairs[gbase[b] + lpos] = vp[i];
        }
    }
}

// ---------------------------------------------------------------------------
// Fat kernel 2: blocks [0, NB) run the per-bucket counting sort (depends only
// on binning); blocks [NB, NB+GEMM1_BLOCKS) run gemm1 (independent of it).
// sort2 hides completely under the longer gemm1.
// ---------------------------------------------------------------------------
union Fat2Smem {
    struct { float f[16 * IN_FEAT]; float part[4 * 16 * OUT_FEAT]; } g;  // 24 KB
    struct { int cnt[NPB]; int cur[NPB]; int wtot; } s;                  // 1 KB
};

__global__ __launch_bounds__(256) void sort2_gemm1_kernel(
        const int* __restrict__ pairs, const int* __restrict__ bcur,
        int* __restrict__ csr, int2* __restrict__ nseg,
        const float* __restrict__ feat, const float* __restrict__ w1,
        ushort* __restrict__ h1) {
    __shared__ Fat2Smem u;
    const int tid = threadIdx.x;

    if (blockIdx.x >= NB) {
        // ---------------- gemm1: feat[16 rows] @ w1 -> bf16 h1 ----------------
        const int c = tid & 63;   // output column
        const int ks = tid >> 6;  // k-slice (32 k each)

        float wr[32];
#pragma unroll
        for (int j = 0; j < 32; ++j)
            wr[j] = w1[(ks * 32 + j) * OUT_FEAT + c];

        const int row0 = (blockIdx.x - NB) * 16;
        const float4* fg = (const float4*)(feat + (size_t)row0 * IN_FEAT);
        float4* fl = (float4*)u.g.f;
        fl[tid] = fg[tid];
        fl[tid + 256] = fg[tid + 256];
        __syncthreads();

        float acc[16];
#pragma unroll
        for (int r = 0; r < 16; ++r) acc[r] = 0.f;

        const float4* fv = (const float4*)u.g.f;
#pragma unroll
        for (int j4 = 0; j4 < 8; ++j4) {
            const float wa = wr[4 * j4], wb = wr[4 * j4 + 1];
            const float wc = wr[4 * j4 + 2], wd = wr[4 * j4 + 3];
#pragma unroll
            for (int r = 0; r < 16; ++r) {
                const float4 a = fv[r * 32 + ks * 8 + j4];  // wave-broadcast
                acc[r] += a.x * wa + a.y * wb + a.z * wc + a.w * wd;
            }
        }

#pragma unroll
        for (int r = 0; r < 16; ++r)
            u.g.part[ks * (16 * OUT_FEAT) + r * OUT_FEAT + c] = acc[r];
        __syncthreads();

        ushort2* h1u2 = (ushort2*)h1;
#pragma unroll
        for (int half = 0; half < 2; ++half) {
            const int idx = half * 256 + tid;
            const int r = idx >> 5;
            const int cp = idx & 31;
            const float* p = u.g.part + r * OUT_FEAT + 2 * cp;
            const float lo = p[0] + p[1024] + p[2048] + p[3072];
            const float hi = p[1] + p[1025] + p[2049] + p[3073];
            h1u2[(size_t)(row0 + r) * 32 + cp] = make_ushort2(f2bf(lo), f2bf(hi));
        }
    } else {
        // ---------------- sort2: per-bucket counting sort ----------------
        const int b = blockIdx.x;
        const int beg = b * CAP;
        const int end = beg + bcur[b];
        if (tid < NPB) u.s.cnt[tid] = 0;
        __syncthreads();
        for (int i = beg + tid; i < end; i += 256)
            atomicAdd(&u.s.cnt[pairs[i] >> 17], 1);
        __syncthreads();
        int v = 0, x = 0;
        const int lane = tid & 63, w = tid >> 6;
        if (tid < NPB) {
            v = u.s.cnt[tid];
            x = v;
#pragma unroll
            for (int off = 1; off < 64; off <<= 1) {
                int y = __shfl_up(x, off);
                if (lane >= off) x += y;
            }
            if (tid == 63) u.s.wtot = x;
        }
        __syncthreads();
        if (tid < NPB) {
            const int gp = beg + (x - v) + (w ? u.s.wtot : 0);
            u.s.cur[tid] = gp;
            nseg[b * NPB + tid] = make_int2(gp, gp + v);
        }
        __syncthreads();
        for (int i = beg + tid; i < end; i += 256) {
            const int p = pairs[i];
            const int pos = atomicAdd(&u.s.cur[p >> 17], 1);
            csr[pos] = (p & 0x1FFFF) << 7;  // byte offset of the src row
        }
    }
}

// ---------------------------------------------------------------------------
// Quad-gather core: 4 rows per wave-load. Lane layout: g = (lane>>4)&3 picks
// the row slot within a quad, q = lane&15 picks a uint2 = 4 bf16 columns
// (cols 4q..4q+3). csr indices: main loop loads 16 at once via one coalesced
// vector load + shfl(bpermute) distribution; remainder quads use scalar
// loads (i is wave-uniform); final <4 edges are masked. Caller gets all-lane
// totals after two shfl_xor merge rounds.
// ---------------------------------------------------------------------------
__device__ __forceinline__ float4 gather_quad(const char* __restrict__ hb,
                                              const int* __restrict__ csr,
                                              int beg, int end, int lane) {
    const int g = (lane >> 4) & 3;
    const unsigned q8 = (unsigned)((lane & 15) * 8);
    float ax = 0.f, ay = 0.f, az = 0.f, aw = 0.f;
    int i = beg;
#define QACC(u)                                   \
    ax += __uint_as_float((u).x << 16);           \
    ay += __uint_as_float((u).x & 0xFFFF0000u);   \
    az += __uint_as_float((u).y << 16);           \
    aw += __uint_as_float((u).y & 0xFFFF0000u)
    for (; i + 16 <= end; i += 16) {
        const int csv = csr[i + (lane & 15)];  // 16 ints, coalesced
        const int r0 = __shfl(csv, g);
        const int r1 = __shfl(csv, 4 + g);
        const int r2 = __shfl(csv, 8 + g);
        const int r3 = __shfl(csv, 12 + g);
        const uint2 u0 = *(const uint2*)(hb + ((unsigned)r0 + q8));
        const uint2 u1 = *(const uint2*)(hb + ((unsigned)r1 + q8));
        const uint2 u2 = *(const uint2*)(hb + ((unsigned)r2 + q8));
        const uint2 u3 = *(const uint2*)(hb + ((unsigned)r3 + q8));
        QACC(u0); QACC(u1); QACC(u2); QACC(u3);
    }
    for (; i + 4 <= end; i += 4) {
        const int c0 = csr[i], c1 = csr[i + 1], c2 = csr[i + 2], c3 = csr[i + 3];
        const int r = g == 0 ? c0 : (g == 1 ? c1 : (g == 2 ? c2 : c3));
        const uint2 u = *(const uint2*)(hb + ((unsigned)r + q8));
        QACC(u);
    }
    if (i < end) {
        const int rem = end - i;  // 1..3
        const int r = csr[i + (g < rem ? g : 0)];
        const uint2 u = *(const uint2*)(hb + ((unsigned)r + q8));
        if (g < rem) { QACC(u); }
    }
#undef QACC
    ax += __shfl_xor(ax, 16); ax += __shfl_xor(ax, 32);
    ay += __shfl_xor(ay, 16); ay += __shfl_xor(ay, 32);
    az += __shfl_xor(az, 16); az += __shfl_xor(az, 32);
    aw += __shfl_xor(aw, 16); aw += __shfl_xor(aw, 32);
    return make_float4(ax, ay, az, aw);
}

__device__ __forceinline__ float4 rrelu4(float4 v) {
    v.x = v.x >= 0.f ? v.x : v.x * SLOPE;
    v.y = v.y >= 0.f ? v.y : v.y * SLOPE;
    v.z = v.z >= 0.f ? v.z : v.z * SLOPE;
    v.w = v.w >= 0.f ? v.w : v.w * SLOPE;
    return v;
}

// ---------------------------------------------------------------------------
// Layer-1 fused: agg(h1) -> rrelu -> @w2 -> bf16 h2. One wave per node.
// ---------------------------------------------------------------------------
__global__ __launch_bounds__(256) void agg_gemm2_kernel(const ushort* __restrict__ h,
                                                        const int* __restrict__ csr,
                                                        const int2* __restrict__ nseg,
                                                        const float* __restrict__ w2,
                                                        ushort* __restrict__ h2) {
    __shared__ float w[OUT_FEAT * OUT_FEAT];  // 16 KB
    __shared__ float rowbuf[4][OUT_FEAT];     // 1 KB, one row per wave
    const int tid = threadIdx.x;

    const float4* w4g = (const float4*)w2;
    float4* wl = (float4*)w;
#pragma unroll
    for (int i = 0; i < 4; ++i) wl[tid + i * 256] = w4g[tid + i * 256];
    __syncthreads();  // w staged (only cross-wave dependency)

    const int wv = tid >> 6, lane = tid & 63, c = tid & 63;
    const int node = blockIdx.x * 4 + wv;  // grid = 25000, all valid
    const int2 seg = nseg[node];
    const int beg = __builtin_amdgcn_readfirstlane(seg.x);
    const int end = __builtin_amdgcn_readfirstlane(seg.y);

    float4 a = gather_quad((const char*)h, csr, beg, end, lane);
    a = rrelu4(a);

    // lanes 0-15 stage the node's 64-col row (intra-wave; no block barrier)
    if ((lane >> 4) == 0) ((float4*)rowbuf[wv])[lane & 15] = a;

    float o = 0.f;
    const float4* rb4 = (const float4*)rowbuf[wv];
#pragma unroll
    for (int k = 0; k < OUT_FEAT; k += 4) {
        const float4 r = rb4[k >> 2];  // wave-uniform broadcast
        o += r.x * w[(k + 0) * OUT_FEAT + c] + r.y * w[(k + 1) * OUT_FEAT + c] +
             r.z * w[(k + 2) * OUT_FEAT + c] + r.w * w[(k + 3) * OUT_FEAT + c];
    }
    h2[(size_t)node * OUT_FEAT + c] = f2bf(o);
}

// ---------------------------------------------------------------------------
// Layer-2 aggregation + fused rrelu -> f32 d_out. One wave per node.
// ---------------------------------------------------------------------------
__global__ __launch_bounds__(256) void agg_rrelu_kernel(const ushort* __restrict__ h,
                                                        const int* __restrict__ csr,
                                                        const int2* __restrict__ nseg,
                                                        float* __restrict__ out) {
    const int tid = threadIdx.x;
    const int lane = tid & 63;
    const int node = blockIdx.x * 4 + (tid >> 6);
    const int2 seg = nseg[node];
    const int beg = __builtin_amdgcn_readfirstlane(seg.x);
    const int end = __builtin_amdgcn_readfirstlane(seg.y);

    float4 a = gather_quad((const char*)h, csr, beg, end, lane);
    if ((lane >> 4) == 0) {
        a = rrelu4(a);
        ((float4*)(out + (size_t)node * OUT_FEAT))[lane & 15] = a;
    }
}

extern "C" void kernel_launch(void* const* d_in, const int* in_sizes, int n_in,
                              void* d_out, int out_size, void* d_ws, size_t ws_size,
                              hipStream_t stream) {
    const float* feat = (const float*)d_in[0];
    const int*   src  = (const int*)d_in[1];
    const int*   dst  = (const int*)d_in[2];
    const float* w1   = (const float*)d_in[3];
    const float* w2   = (const float*)d_in[4];
    float* out = (float*)d_out;

    // workspace layout (pairs aliases h2: pairs is dead before h2 is written)
    ushort* h1   = (ushort*)d_ws;                             // 12.8 MB
    ushort* h2   = h1 + (size_t)N_NODES * OUT_FEAT;           // 12.8 MB
    int*    pairs = (int*)h2;                                 // 8.0 MB (alias)
    int*    csr  = (int*)(h2 + (size_t)N_NODES * OUT_FEAT);   // NB*CAP = 8.0 MB
    int2*   nseg = (int2*)(csr + NB * CAP);                   // 0.8 MB
    int*    bcur = (int*)(nseg + NB * NPB);                   // NB

    // ---- binning, then [sort2 || gemm1] (sort2 hides under gemm1) ----
    hipMemsetAsync(bcur, 0, NB * sizeof(int), stream);
    binning_kernel<<<BIN_BLOCKS, 256, 0, stream>>>(src, dst, bcur, pairs);
    sort2_gemm1_kernel<<<NB + GEMM1_BLOCKS, 256, 0, stream>>>(
        pairs, bcur, csr, nseg, feat, w1, h1);

    // ---- layer 1 (gemm2 fused into aggregation) ----
    agg_gemm2_kernel<<<N_NODES / 4, 256, 0, stream>>>(h1, csr, nseg, w2, h2);

    // ---- layer 2 ----
    agg_rrelu_kernel<<<N_NODES / 4, 256, 0, stream>>>(h2, csr, nseg, out);
}

// Round 12
// 189.485 us; speedup vs baseline: 1.0029x; 1.0029x over previous
//
#include <hip/hip_runtime.h>

#define N_NODES 100000
#define N_EDGES 1600000
#define IN_FEAT 128
#define OUT_FEAT 64
#define SLOPE 0.22916666666666666f  // (1/8 + 1/3)/2 = 11/48

#define NPB 128            // nodes per bucket
#define NB 782             // ceil(N_NODES / NPB)
#define CAP 2560           // static bucket capacity (mean 2046 -> 11+ sigma margin)
#define BIN_CHUNK 8192     // edges per binning block
#define EPT 32             // edges per thread in binning (BIN_CHUNK/256)
#define BIN_BLOCKS ((N_EDGES + BIN_CHUNK - 1) / BIN_CHUNK)  // 196
#define GEMM1_BLOCKS (N_NODES / 16)                         // 6250

__device__ __forceinline__ ushort f2bf(float x) {
    unsigned u = __float_as_uint(x);
    u += 0x7FFFu + ((u >> 16) & 1u);  // round to nearest even
    return (ushort)(u >> 16);
}

// ---------------------------------------------------------------------------
// Binning (standalone): dense per-block runs of packed ((dst&127)<<17 | src)
// into static per-bucket windows [b*CAP, (b+1)*CAP).
// ---------------------------------------------------------------------------
__global__ __launch_bounds__(256) void binning_kernel(const int* __restrict__ src,
                                                      const int* __restrict__ dst,
                                                      int* __restrict__ bcur,
                                                      int* __restrict__ pairs) {
    __shared__ int cnt[NB];
    __shared__ int gbase[NB];
    for (int i = threadIdx.x; i < NB; i += 256) cnt[i] = 0;
    __syncthreads();
    const int base = blockIdx.x * BIN_CHUNK;
    int bl[EPT];  // (bucket<<13) | local_rank, or -1
    int vp[EPT];  // packed payload
#pragma unroll
    for (int i = 0; i < EPT; ++i) {
        const int e = base + i * 256 + threadIdx.x;
        if (e < N_EDGES) {
            const int d = dst[e];
            const int b = d >> 7;
            const int lpos = atomicAdd(&cnt[b], 1);
            bl[i] = (b << 13) | lpos;
            vp[i] = ((d & 127) << 17) | src[e];
        } else {
            bl[i] = -1;
        }
    }
    __syncthreads();
    for (int i = threadIdx.x; i < NB; i += 256) {
        const int c = cnt[i];
        gbase[i] = c ? (i * CAP + atomicAdd(&bcur[i], c)) : 0;
    }
    __syncthreads();
#pragma unroll
    for (int i = 0; i < EPT; ++i) {
        if (bl[i] >= 0) {
            const int b = bl[i] >> 13, lpos = bl[i] & 8191;
            pairs[gbase[b] + lpos] = vp[i];
        }
    }
}

// ---------------------------------------------------------------------------
// Fat kernel 2: blocks [0, NB) run the per-bucket counting sort (depends only
// on binning); blocks [NB, NB+GEMM1_BLOCKS) run gemm1 (independent of it).
// sort2 hides completely under the longer gemm1.
// ---------------------------------------------------------------------------
union Fat2Smem {
    struct { float f[16 * IN_FEAT]; float part[4 * 16 * OUT_FEAT]; } g;  // 24 KB
    struct { int cnt[NPB]; int cur[NPB]; int wtot; } s;                  // 1 KB
};

__global__ __launch_bounds__(256) void sort2_gemm1_kernel(
        const int* __restrict__ pairs, const int* __restrict__ bcur,
        int* __restrict__ csr, int2* __restrict__ nseg,
        const float* __restrict__ feat, const float* __restrict__ w1,
        ushort* __restrict__ h1) {
    __shared__ Fat2Smem u;
    const int tid = threadIdx.x;

    if (blockIdx.x >= NB) {
        // ---------------- gemm1: feat[16 rows] @ w1 -> bf16 h1 ----------------
        const int c = tid & 63;   // output column
        const int ks = tid >> 6;  // k-slice (32 k each)

        float wr[32];
#pragma unroll
        for (int j = 0; j < 32; ++j)
            wr[j] = w1[(ks * 32 + j) * OUT_FEAT + c];

        const int row0 = (blockIdx.x - NB) * 16;
        const float4* fg = (const float4*)(feat + (size_t)row0 * IN_FEAT);
        float4* fl = (float4*)u.g.f;
        fl[tid] = fg[tid];
        fl[tid + 256] = fg[tid + 256];
        __syncthreads();

        float acc[16];
#pragma unroll
        for (int r = 0; r < 16; ++r) acc[r] = 0.f;

        const float4* fv = (const float4*)u.g.f;
#pragma unroll
        for (int j4 = 0; j4 < 8; ++j4) {
            const float wa = wr[4 * j4], wb = wr[4 * j4 + 1];
            const float wc = wr[4 * j4 + 2], wd = wr[4 * j4 + 3];
#pragma unroll
            for (int r = 0; r < 16; ++r) {
                const float4 a = fv[r * 32 + ks * 8 + j4];  // wave-broadcast
                acc[r] += a.x * wa + a.y * wb + a.z * wc + a.w * wd;
            }
        }

#pragma unroll
        for (int r = 0; r < 16; ++r)
            u.g.part[ks * (16 * OUT_FEAT) + r * OUT_FEAT + c] = acc[r];
        __syncthreads();

        ushort2* h1u2 = (ushort2*)h1;
#pragma unroll
        for (int half = 0; half < 2; ++half) {
            const int idx = half * 256 + tid;
            const int r = idx >> 5;
            const int cp = idx & 31;
            const float* p = u.g.part + r * OUT_FEAT + 2 * cp;
            const float lo = p[0] + p[1024] + p[2048] + p[3072];
            const float hi = p[1] + p[1025] + p[2049] + p[3073];
            h1u2[(size_t)(row0 + r) * 32 + cp] = make_ushort2(f2bf(lo), f2bf(hi));
        }
    } else {
        // ---------------- sort2: per-bucket counting sort ----------------
        const int b = blockIdx.x;
        const int beg = b * CAP;
        const int end = beg + bcur[b];
        if (tid < NPB) u.s.cnt[tid] = 0;
        __syncthreads();
        for (int i = beg + tid; i < end; i += 256)
            atomicAdd(&u.s.cnt[pairs[i] >> 17], 1);
        __syncthreads();
        int v = 0, x = 0;
        const int lane = tid & 63, w = tid >> 6;
        if (tid < NPB) {
            v = u.s.cnt[tid];
            x = v;
#pragma unroll
            for (int off = 1; off < 64; off <<= 1) {
                int y = __shfl_up(x, off);
                if (lane >= off) x += y;
            }
            if (tid == 63) u.s.wtot = x;
        }
        __syncthreads();
        if (tid < NPB) {
            const int gp = beg + (x - v) + (w ? u.s.wtot : 0);
            u.s.cur[tid] = gp;
            nseg[b * NPB + tid] = make_int2(gp, gp + v);
        }
        __syncthreads();
        for (int i = beg + tid; i < end; i += 256) {
            const int p = pairs[i];
            const int pos = atomicAdd(&u.s.cur[p >> 17], 1);
            csr[pos] = (p & 0x1FFFF) << 7;  // byte offset of the src row
        }
    }
}

// ---------------------------------------------------------------------------
// Quad-gather core: 4 rows per wave-load. Lane layout: g = (lane>>4)&3 picks
// the row slot within a quad, q = lane&15 picks a uint2 = 4 bf16 columns
// (cols 4q..4q+3). csr indices: main loop loads 16 at once via one coalesced
// vector load + shfl(bpermute) distribution; remainder quads use scalar
// loads (i is wave-uniform); final <4 edges are masked. Caller gets all-lane
// totals after two shfl_xor merge rounds.
// ---------------------------------------------------------------------------
__device__ __forceinline__ float4 gather_quad(const char* __restrict__ hb,
                                              const int* __restrict__ csr,
                                              int beg, int end, int lane) {
    const int g = (lane >> 4) & 3;
    const unsigned q8 = (unsigned)((lane & 15) * 8);
    float ax = 0.f, ay = 0.f, az = 0.f, aw = 0.f;
    int i = beg;
#define QACC(u)                                   \
    ax += __uint_as_float((u).x << 16);           \
    ay += __uint_as_float((u).x & 0xFFFF0000u);   \
    az += __uint_as_float((u).y << 16);           \
    aw += __uint_as_float((u).y & 0xFFFF0000u)
    for (; i + 16 <= end; i += 16) {
        const int csv = csr[i + (lane & 15)];  // 16 ints, coalesced
        const int r0 = __shfl(csv, g);
        const int r1 = __shfl(csv, 4 + g);
        const int r2 = __shfl(csv, 8 + g);
        const int r3 = __shfl(csv, 12 + g);
        const uint2 u0 = *(const uint2*)(hb + ((unsigned)r0 + q8));
        const uint2 u1 = *(const uint2*)(hb + ((unsigned)r1 + q8));
        const uint2 u2 = *(const uint2*)(hb + ((unsigned)r2 + q8));
        const uint2 u3 = *(const uint2*)(hb + ((unsigned)r3 + q8));
        QACC(u0); QACC(u1); QACC(u2); QACC(u3);
    }
    for (; i + 4 <= end; i += 4) {
        const int c0 = csr[i], c1 = csr[i + 1], c2 = csr[i + 2], c3 = csr[i + 3];
        const int r = g == 0 ? c0 : (g == 1 ? c1 : (g == 2 ? c2 : c3));
        const uint2 u = *(const uint2*)(hb + ((unsigned)r + q8));
        QACC(u);
    }
    if (i < end) {
        const int rem = end - i;  // 1..3
        const int r = csr[i + (g < rem ? g : 0)];
        const uint2 u = *(const uint2*)(hb + ((unsigned)r + q8));
        if (g < rem) { QACC(u); }
    }
#undef QACC
    ax += __shfl_xor(ax, 16); ax += __shfl_xor(ax, 32);
    ay += __shfl_xor(ay, 16); ay += __shfl_xor(ay, 32);
    az += __shfl_xor(az, 16); az += __shfl_xor(az, 32);
    aw += __shfl_xor(aw, 16); aw += __shfl_xor(aw, 32);
    return make_float4(ax, ay, az, aw);
}

__device__ __forceinline__ float4 rrelu4(float4 v) {
    v.x = v.x >= 0.f ? v.x : v.x * SLOPE;
    v.y = v.y >= 0.f ? v.y : v.y * SLOPE;
    v.z = v.z >= 0.f ? v.z : v.z * SLOPE;
    v.w = v.w >= 0.f ? v.w : v.w * SLOPE;
    return v;
}

// ---------------------------------------------------------------------------
// Layer-1 fused: agg(h1) -> rrelu -> @w2 -> bf16 h2. One wave per node.
// ---------------------------------------------------------------------------
__global__ __launch_bounds__(256) void agg_gemm2_kernel(const ushort* __restrict__ h,
                                                        const int* __restrict__ csr,
                                                        const int2* __restrict__ nseg,
                                                        const float* __restrict__ w2,
                                                        ushort* __restrict__ h2) {
    __shared__ float w[OUT_FEAT * OUT_FEAT];  // 16 KB
    __shared__ float rowbuf[4][OUT_FEAT];     // 1 KB, one row per wave
    const int tid = threadIdx.x;

    const float4* w4g = (const float4*)w2;
    float4* wl = (float4*)w;
#pragma unroll
    for (int i = 0; i < 4; ++i) wl[tid + i * 256] = w4g[tid + i * 256];
    __syncthreads();  // w staged (only cross-wave dependency)

    const int wv = tid >> 6, lane = tid & 63, c = tid & 63;
    const int node = blockIdx.x * 4 + wv;  // grid = 25000, all valid
    const int2 seg = nseg[node];
    const int beg = __builtin_amdgcn_readfirstlane(seg.x);
    const int end = __builtin_amdgcn_readfirstlane(seg.y);

    float4 a = gather_quad((const char*)h, csr, beg, end, lane);
    a = rrelu4(a);

    // lanes 0-15 stage the node's 64-col row (intra-wave; no block barrier)
    if ((lane >> 4) == 0) ((float4*)rowbuf[wv])[lane & 15] = a;

    float o = 0.f;
    const float4* rb4 = (const float4*)rowbuf[wv];
#pragma unroll
    for (int k = 0; k < OUT_FEAT; k += 4) {
        const float4 r = rb4[k >> 2];  // wave-uniform broadcast
        o += r.x * w[(k + 0) * OUT_FEAT + c] + r.y * w[(k + 1) * OUT_FEAT + c] +
             r.z * w[(k + 2) * OUT_FEAT + c] + r.w * w[(k + 3) * OUT_FEAT + c];
    }
    h2[(size_t)node * OUT_FEAT + c] = f2bf(o);
}

// ---------------------------------------------------------------------------
// Layer-2 aggregation + fused rrelu -> f32 d_out. One wave per node.
// ---------------------------------------------------------------------------
__global__ __launch_bounds__(256) void agg_rrelu_kernel(const ushort* __restrict__ h,
                                                        const int* __restrict__ csr,
                                                        const int2* __restrict__ nseg,
                                                        float* __restrict__ out) {
    const int tid = threadIdx.x;
    const int lane = tid & 63;
    const int node = blockIdx.x * 4 + (tid >> 6);
    const int2 seg = nseg[node];
    const int beg = __builtin_amdgcn_readfirstlane(seg.x);
    const int end = __builtin_amdgcn_readfirstlane(seg.y);

    float4 a = gather_quad((const char*)h, csr, beg, end, lane);
    if ((lane >> 4) == 0) {
        a = rrelu4(a);
        ((float4*)(out + (size_t)node * OUT_FEAT))[lane & 15] = a;
    }
}

extern "C" void kernel_launch(void* const* d_in, const int* in_sizes, int n_in,
                              void* d_out, int out_size, void* d_ws, size_t ws_size,
                              hipStream_t stream) {
    const float* feat = (const float*)d_in[0];
    const int*   src  = (const int*)d_in[1];
    const int*   dst  = (const int*)d_in[2];
    const float* w1   = (const float*)d_in[3];
    const float* w2   = (const float*)d_in[4];
    float* out = (float*)d_out;

    // workspace layout (pairs aliases h2: pairs is dead before h2 is written)
    ushort* h1   = (ushort*)d_ws;                             // 12.8 MB
    ushort* h2   = h1 + (size_t)N_NODES * OUT_FEAT;           // 12.8 MB
    int*    pairs = (int*)h2;                                 // 8.0 MB (alias)
    int*    csr  = (int*)(h2 + (size_t)N_NODES * OUT_FEAT);   // NB*CAP = 8.0 MB
    int2*   nseg = (int2*)(csr + NB * CAP);                   // 0.8 MB
    int*    bcur = (int*)(nseg + NB * NPB);                   // NB

    // ---- binning, then [sort2 || gemm1] (sort2 hides under gemm1) ----
    hipMemsetAsync(bcur, 0, NB * sizeof(int), stream);
    binning_kernel<<<BIN_BLOCKS, 256, 0, stream>>>(src, dst, bcur, pairs);
    sort2_gemm1_kernel<<<NB + GEMM1_BLOCKS, 256, 0, stream>>>(
        pairs, bcur, csr, nseg, feat, w1, h1);

    // ---- layer 1 (gemm2 fused into aggregation) ----
    agg_gemm2_kernel<<<N_NODES / 4, 256, 0, stream>>>(h1, csr, nseg, w2, h2);

    // ---- layer 2 ----
    agg_rrelu_kernel<<<N_NODES / 4, 256, 0, stream>>>(h2, csr, nseg, out);
}

// Round 13
// 178.116 us; speedup vs baseline: 1.0669x; 1.0638x over previous
//
#include <hip/hip_runtime.h>

#define N_NODES 100000
#define N_EDGES 1600000
#define IN_FEAT 128
#define OUT_FEAT 64
#define SLOPE 0.22916666666666666f  // (1/8 + 1/3)/2 = 11/48

#define NPB 128            // nodes per bucket
#define NB 782             // ceil(N_NODES / NPB)
#define CAP 2560           // static bucket capacity (mean 2046 -> 11+ sigma margin)
#define BIN_CHUNK 8192     // edges per binning block
#define EPT 32             // edges per thread in binning (BIN_CHUNK/256)
#define BIN_BLOCKS ((N_EDGES + BIN_CHUNK - 1) / BIN_CHUNK)  // 196
#define GEMM1_BLOCKS (N_NODES / 16)                         // 6250
#define WTS 68             // padded stride (floats) of transposed w2 rows

__device__ __forceinline__ ushort f2bf(float x) {
    unsigned u = __float_as_uint(x);
    u += 0x7FFFu + ((u >> 16) & 1u);  // round to nearest even
    return (ushort)(u >> 16);
}

// ---------------------------------------------------------------------------
// Binning (standalone): dense per-block runs of packed ((dst&127)<<17 | src)
// into static per-bucket windows [b*CAP, (b+1)*CAP).
// ---------------------------------------------------------------------------
__global__ __launch_bounds__(256) void binning_kernel(const int* __restrict__ src,
                                                      const int* __restrict__ dst,
                                                      int* __restrict__ bcur,
                                                      int* __restrict__ pairs) {
    __shared__ int cnt[NB];
    __shared__ int gbase[NB];
    for (int i = threadIdx.x; i < NB; i += 256) cnt[i] = 0;
    __syncthreads();
    const int base = blockIdx.x * BIN_CHUNK;
    int bl[EPT];  // (bucket<<13) | local_rank, or -1
    int vp[EPT];  // packed payload
#pragma unroll
    for (int i = 0; i < EPT; ++i) {
        const int e = base + i * 256 + threadIdx.x;
        if (e < N_EDGES) {
            const int d = dst[e];
            const int b = d >> 7;
            const int lpos = atomicAdd(&cnt[b], 1);
            bl[i] = (b << 13) | lpos;
            vp[i] = ((d & 127) << 17) | src[e];
        } else {
            bl[i] = -1;
        }
    }
    __syncthreads();
    for (int i = threadIdx.x; i < NB; i += 256) {
        const int c = cnt[i];
        gbase[i] = c ? (i * CAP + atomicAdd(&bcur[i], c)) : 0;
    }
    __syncthreads();
#pragma unroll
    for (int i = 0; i < EPT; ++i) {
        if (bl[i] >= 0) {
            const int b = bl[i] >> 13, lpos = bl[i] & 8191;
            pairs[gbase[b] + lpos] = vp[i];
        }
    }
}

// ---------------------------------------------------------------------------
// Fat kernel: blocks [0, NB) run the per-bucket counting sort (depends only
// on binning); blocks [NB, NB+GEMM1_BLOCKS) run gemm1 (independent of it).
// sort2 hides completely under the longer gemm1.
// ---------------------------------------------------------------------------
union Fat2Smem {
    struct { float f[16 * IN_FEAT]; float part[4 * 16 * OUT_FEAT]; } g;  // 24 KB
    struct { int cnt[NPB]; int cur[NPB]; int wtot; } s;                  // 1 KB
};

__global__ __launch_bounds__(256) void sort2_gemm1_kernel(
        const int* __restrict__ pairs, const int* __restrict__ bcur,
        int* __restrict__ csr, int2* __restrict__ nseg,
        const float* __restrict__ feat, const float* __restrict__ w1,
        ushort* __restrict__ h1) {
    __shared__ Fat2Smem u;
    const int tid = threadIdx.x;

    if (blockIdx.x >= NB) {
        // ---------------- gemm1: feat[16 rows] @ w1 -> bf16 h1 ----------------
        const int c = tid & 63;   // output column
        const int ks = tid >> 6;  // k-slice (32 k each)

        float wr[32];
#pragma unroll
        for (int j = 0; j < 32; ++j)
            wr[j] = w1[(ks * 32 + j) * OUT_FEAT + c];

        const int row0 = (blockIdx.x - NB) * 16;
        const float4* fg = (const float4*)(feat + (size_t)row0 * IN_FEAT);
        float4* fl = (float4*)u.g.f;
        fl[tid] = fg[tid];
        fl[tid + 256] = fg[tid + 256];
        __syncthreads();

        float acc[16];
#pragma unroll
        for (int r = 0; r < 16; ++r) acc[r] = 0.f;

        const float4* fv = (const float4*)u.g.f;
#pragma unroll
        for (int j4 = 0; j4 < 8; ++j4) {
            const float wa = wr[4 * j4], wb = wr[4 * j4 + 1];
            const float wc = wr[4 * j4 + 2], wd = wr[4 * j4 + 3];
#pragma unroll
            for (int r = 0; r < 16; ++r) {
                const float4 a = fv[r * 32 + ks * 8 + j4];  // wave-broadcast
                acc[r] += a.x * wa + a.y * wb + a.z * wc + a.w * wd;
            }
        }

#pragma unroll
        for (int r = 0; r < 16; ++r)
            u.g.part[ks * (16 * OUT_FEAT) + r * OUT_FEAT + c] = acc[r];
        __syncthreads();

        ushort2* h1u2 = (ushort2*)h1;
#pragma unroll
        for (int half = 0; half < 2; ++half) {
            const int idx = half * 256 + tid;
            const int r = idx >> 5;
            const int cp = idx & 31;
            const float* p = u.g.part + r * OUT_FEAT + 2 * cp;
            const float lo = p[0] + p[1024] + p[2048] + p[3072];
            const float hi = p[1] + p[1025] + p[2049] + p[3073];
            h1u2[(size_t)(row0 + r) * 32 + cp] = make_ushort2(f2bf(lo), f2bf(hi));
        }
    } else {
        // ---------------- sort2: per-bucket counting sort ----------------
        const int b = blockIdx.x;
        const int beg = b * CAP;
        const int end = beg + bcur[b];
        if (tid < NPB) u.s.cnt[tid] = 0;
        __syncthreads();
        for (int i = beg + tid; i < end; i += 256)
            atomicAdd(&u.s.cnt[pairs[i] >> 17], 1);
        __syncthreads();
        int v = 0, x = 0;
        const int lane = tid & 63, w = tid >> 6;
        if (tid < NPB) {
            v = u.s.cnt[tid];
            x = v;
#pragma unroll
            for (int off = 1; off < 64; off <<= 1) {
                int y = __shfl_up(x, off);
                if (lane >= off) x += y;
            }
            if (tid == 63) u.s.wtot = x;
        }
        __syncthreads();
        if (tid < NPB) {
            const int gp = beg + (x - v) + (w ? u.s.wtot : 0);
            u.s.cur[tid] = gp;
            nseg[b * NPB + tid] = make_int2(gp, gp + v);
        }
        __syncthreads();
        for (int i = beg + tid; i < end; i += 256) {
            const int p = pairs[i];
            const int pos = atomicAdd(&u.s.cur[p >> 17], 1);
            csr[pos] = (p & 0x1FFFF) << 7;  // byte offset of the src row
        }
    }
}

// ---------------------------------------------------------------------------
// Pair-gather core (round-10 version, measured best): lanes 0-31 read row
// csr[i], lanes 32-63 read row csr[i+1]; each lane loads a uint = 2 bf16
// columns {2cp, 2cp+1}. Caller merges halves with shfl_xor(32).
// ---------------------------------------------------------------------------
__device__ __forceinline__ float2 gather_pairs(const char* __restrict__ hb,
                                               const int* __restrict__ csr,
                                               int beg, int end, int hi, int cp4) {
    float ax = 0.f, ay = 0.f;
    int i = beg;
#define LOADU(k) const unsigned u##k = *(const unsigned*)(hb + (unsigned)(csr[i + 2*(k) + hi] + cp4))
#define ACCU(k)                                            \
    ax += __uint_as_float(u##k << 16);                     \
    ay += __uint_as_float(u##k & 0xFFFF0000u)
    for (; i + 16 <= end; i += 16) {  // 8 pair-rounds = 16 edges
        LOADU(0); LOADU(1); LOADU(2); LOADU(3);
        LOADU(4); LOADU(5); LOADU(6); LOADU(7);
        ACCU(0); ACCU(1); ACCU(2); ACCU(3);
        ACCU(4); ACCU(5); ACCU(6); ACCU(7);
    }
    if (i + 8 <= end) {
        LOADU(0); LOADU(1); LOADU(2); LOADU(3);
        ACCU(0); ACCU(1); ACCU(2); ACCU(3);
        i += 8;
    }
    if (i + 4 <= end) {
        LOADU(0); LOADU(1);
        ACCU(0); ACCU(1);
        i += 4;
    }
    for (; i < end; i += 2) {
        if (i + hi < end) {
            const unsigned u = *(const unsigned*)(hb + (unsigned)(csr[i + hi] + cp4));
            ax += __uint_as_float(u << 16);
            ay += __uint_as_float(u & 0xFFFF0000u);
        }
    }
#undef LOADU
#undef ACCU
    return make_float2(ax, ay);
}

// ---------------------------------------------------------------------------
// Layer-1 fused: agg(h1) -> rrelu -> @w2 -> bf16 h2. One wave per node.
// w2 staged TRANSPOSED in LDS (row c = w2[:,c], pad-stride 68 floats) so the
// gemm tail is 16 ds_read_b128 per thread instead of 128 ds_read_b32.
// ---------------------------------------------------------------------------
__global__ __launch_bounds__(256) void agg_gemm2_kernel(const ushort* __restrict__ h,
                                                        const int* __restrict__ csr,
                                                        const int2* __restrict__ nseg,
                                                        const float* __restrict__ w2,
                                                        ushort* __restrict__ h2) {
    __shared__ float wt[OUT_FEAT * WTS];   // 17 KB transposed w2
    __shared__ float rowbuf[4][OUT_FEAT];  // 1 KB, one row per wave
    const int tid = threadIdx.x;
    const int c = tid & 63;

    // stage w2 transposed: wave kb covers k = kb*16 .. kb*16+15 for all c
    {
        const int kb = tid >> 6;
#pragma unroll
        for (int j = 0; j < 16; ++j) {
            const int k = kb * 16 + j;
            wt[c * WTS + k] = w2[k * OUT_FEAT + c];  // coalesced 256B per j
        }
    }
    __syncthreads();  // wt staged (only cross-wave dependency)

    const int wv = tid >> 6;
    const int hi = (tid >> 5) & 1, cp = tid & 31;
    const int node = blockIdx.x * 4 + wv;  // grid = 25000, all valid
    const int2 seg = nseg[node];
    const int beg = __builtin_amdgcn_readfirstlane(seg.x);
    const int end = __builtin_amdgcn_readfirstlane(seg.y);

    float2 acc = gather_pairs((const char*)h, csr, beg, end, hi, cp * 4);
    acc.x += __shfl_xor(acc.x, 32);
    acc.y += __shfl_xor(acc.y, 32);
    acc.x = acc.x >= 0.f ? acc.x : acc.x * SLOPE;
    acc.y = acc.y >= 0.f ? acc.y : acc.y * SLOPE;

    // stage the node's row (intra-wave only; no block barrier needed)
    if (hi == 0) ((float2*)rowbuf[wv])[cp] = acc;

    float o = 0.f;
    const float4* rb4 = (const float4*)rowbuf[wv];
    const float4* wt4 = (const float4*)(wt + c * WTS);  // 272B stride, 16B-aligned
#pragma unroll
    for (int j4 = 0; j4 < 16; ++j4) {
        const float4 r = rb4[j4];  // wave-uniform broadcast
        const float4 v = wt4[j4];  // b128, 8-way alias = b128 floor rate
        o += r.x * v.x + r.y * v.y + r.z * v.z + r.w * v.w;
    }
    h2[(size_t)node * OUT_FEAT + c] = f2bf(o);
}

// ---------------------------------------------------------------------------
// Layer-2 aggregation + fused rrelu -> f32 d_out. One wave per node.
// ---------------------------------------------------------------------------
__global__ __launch_bounds__(256) void agg_rrelu_kernel(const ushort* __restrict__ h,
                                                        const int* __restrict__ csr,
                                                        const int2* __restrict__ nseg,
                                                        float* __restrict__ out) {
    const int tid = threadIdx.x;
    const int hi = (tid >> 5) & 1, cp = tid & 31;
    const int node = blockIdx.x * 4 + (tid >> 6);
    const int2 seg = nseg[node];
    const int beg = __builtin_amdgcn_readfirstlane(seg.x);
    const int end = __builtin_amdgcn_readfirstlane(seg.y);

    float2 acc = gather_pairs((const char*)h, csr, beg, end, hi, cp * 4);
    acc.x += __shfl_xor(acc.x, 32);
    acc.y += __shfl_xor(acc.y, 32);
    if (hi == 0) {
        acc.x = acc.x >= 0.f ? acc.x : acc.x * SLOPE;
        acc.y = acc.y >= 0.f ? acc.y : acc.y * SLOPE;
        ((float2*)(out + (size_t)node * OUT_FEAT))[cp] = acc;
    }
}

extern "C" void kernel_launch(void* const* d_in, const int* in_sizes, int n_in,
                              void* d_out, int out_size, void* d_ws, size_t ws_size,
                              hipStream_t stream) {
    const float* feat = (const float*)d_in[0];
    const int*   src  = (const int*)d_in[1];
    const int*   dst  = (const int*)d_in[2];
    const float* w1   = (const float*)d_in[3];
    const float* w2   = (const float*)d_in[4];
    float* out = (float*)d_out;

    // workspace layout (pairs aliases h2: pairs is dead before h2 is written)
    ushort* h1   = (ushort*)d_ws;                             // 12.8 MB
    ushort* h2   = h1 + (size_t)N_NODES * OUT_FEAT;           // 12.8 MB
    int*    pairs = (int*)h2;                                 // 8.0 MB (alias)
    int*    csr  = (int*)(h2 + (size_t)N_NODES * OUT_FEAT);   // NB*CAP = 8.0 MB
    int2*   nseg = (int2*)(csr + NB * CAP);                   // 0.8 MB
    int*    bcur = (int*)(nseg + NB * NPB);                   // NB

    // ---- binning, then [sort2 || gemm1] (sort2 hides under gemm1) ----
    hipMemsetAsync(bcur, 0, NB * sizeof(int), stream);
    binning_kernel<<<BIN_BLOCKS, 256, 0, stream>>>(src, dst, bcur, pairs);
    sort2_gemm1_kernel<<<NB + GEMM1_BLOCKS, 256, 0, stream>>>(
        pairs, bcur, csr, nseg, feat, w1, h1);

    // ---- layer 1 (gemm2 fused into aggregation) ----
    agg_gemm2_kernel<<<N_NODES / 4, 256, 0, stream>>>(h1, csr, nseg, w2, h2);

    // ---- layer 2 ----
    agg_rrelu_kernel<<<N_NODES / 4, 256, 0, stream>>>(h2, csr, nseg, out);
}